// Round 9
// baseline (2988.130 us; speedup 1.0000x reference)
//
#include <hip/hip_runtime.h>
#include <hip/hip_bf16.h>

// Problem constants
#define Tt 4096   // B*L tokens
#define Dd 1024   // model dim
#define Ee 8      // experts
#define Kk 2      // top-k
#define Ff 4096   // DFF

using f32x4  = __attribute__((ext_vector_type(4))) float;
using bf16x8 = __attribute__((ext_vector_type(8))) short;

__device__ __forceinline__ unsigned short f2bf(float f) {
    union { float fp; unsigned int u; } v; v.fp = f;
    unsigned int u = v.u;
    return (unsigned short)((u + 0x7FFFu + ((u >> 16) & 1u)) >> 16);  // RNE
}

__device__ __forceinline__ void gl16(const void* g, void* l) {
    __builtin_amdgcn_global_load_lds(
        (const __attribute__((address_space(1))) void*)g,
        (__attribute__((address_space(3))) void*)l, 16, 0, 0);
}

// ---------------- Router (+ x->bf16): logits fp64, softmax, top-2, renorm ----------------
__global__ void router_kernel(const float* __restrict__ x, const float* __restrict__ Wr,
                              int* __restrict__ ids, float* __restrict__ wts,
                              int* __restrict__ counts, unsigned short* __restrict__ xb) {
    const int t = blockIdx.x;
    const int lane = threadIdx.x;  // 64
    const float* xr = x + (size_t)t * Dd + lane * 16;
    float xv[16];
#pragma unroll
    for (int i = 0; i < 4; ++i) *(float4*)(xv + 4 * i) = *(const float4*)(xr + 4 * i);
    uint4 o0, o1;
    o0.x = (unsigned)f2bf(xv[0])  | ((unsigned)f2bf(xv[1])  << 16);
    o0.y = (unsigned)f2bf(xv[2])  | ((unsigned)f2bf(xv[3])  << 16);
    o0.z = (unsigned)f2bf(xv[4])  | ((unsigned)f2bf(xv[5])  << 16);
    o0.w = (unsigned)f2bf(xv[6])  | ((unsigned)f2bf(xv[7])  << 16);
    o1.x = (unsigned)f2bf(xv[8])  | ((unsigned)f2bf(xv[9])  << 16);
    o1.y = (unsigned)f2bf(xv[10]) | ((unsigned)f2bf(xv[11]) << 16);
    o1.z = (unsigned)f2bf(xv[12]) | ((unsigned)f2bf(xv[13]) << 16);
    o1.w = (unsigned)f2bf(xv[14]) | ((unsigned)f2bf(xv[15]) << 16);
    unsigned short* xo = xb + (size_t)t * Dd + lane * 16;
    *(uint4*)(xo) = o0;
    *(uint4*)(xo + 8) = o1;

    double dot[Ee];
#pragma unroll
    for (int e = 0; e < Ee; ++e) {
        const float* wr = Wr + e * Dd + lane * 16;
        double s = 0.0;
#pragma unroll
        for (int i = 0; i < 16; ++i) s += (double)xv[i] * (double)wr[i];
        dot[e] = s;
    }
#pragma unroll
    for (int off = 32; off >= 1; off >>= 1) {
#pragma unroll
        for (int e = 0; e < Ee; ++e) dot[e] += __shfl_xor(dot[e], off, 64);
    }
    if (lane == 0) {
        float lg[Ee];
#pragma unroll
        for (int e = 0; e < Ee; ++e) lg[e] = (float)dot[e];
        float m = lg[0];
        for (int e = 1; e < Ee; ++e) m = fmaxf(m, lg[e]);
        float ex[Ee]; float sum = 0.f;
        for (int e = 0; e < Ee; ++e) { ex[e] = expf(lg[e] - m); sum += ex[e]; }
        float s0 = -1.f, s1 = -1.f; int i0 = 0, i1 = 0;
        for (int e = 0; e < Ee; ++e) {
            float s = ex[e];
            if (s > s0)      { s1 = s0; i1 = i0; s0 = s; i0 = e; }
            else if (s > s1) { s1 = s; i1 = e; }
        }
        float inv = 1.f / sum;
        float sc0 = s0 * inv, sc1 = s1 * inv;
        float den = sc0 + sc1 + 1.1920929e-7f;
        ids[2 * t] = i0; ids[2 * t + 1] = i1;
        wts[2 * t] = sc0 / den; wts[2 * t + 1] = sc1 / den;
        atomicAdd(&counts[i0], 1);
        atomicAdd(&counts[i1], 1);
    }
}

// ---------------- combined weight convert: Wgu interleave + Wd plain ----------------
__global__ void cvt_all_kernel(const float* __restrict__ Wg, const float* __restrict__ Wu,
                               const float* __restrict__ Wd,
                               unsigned short* __restrict__ Wgu, unsigned short* __restrict__ Wdb) {
    const int bid = blockIdx.x;
    if (bid < 32768) {
        size_t tid = (size_t)bid * blockDim.x + threadIdx.x;
        size_t row = tid >> 7;
        int dc  = (int)(tid & 127);
        int e   = (int)(row >> 13);
        int j   = (int)(row & 8191);
        int fg = j >> 5, s = (j >> 4) & 1, fi = j & 15;
        int f  = fg * 16 + fi;
        const float* src = (s ? Wu : Wg) + ((size_t)e * Ff + f) * Dd + dc * 8;
        float4 a = *(const float4*)(src);
        float4 b = *(const float4*)(src + 4);
        uint4 o;
        o.x = (unsigned)f2bf(a.x) | ((unsigned)f2bf(a.y) << 16);
        o.y = (unsigned)f2bf(a.z) | ((unsigned)f2bf(a.w) << 16);
        o.z = (unsigned)f2bf(b.x) | ((unsigned)f2bf(b.y) << 16);
        o.w = (unsigned)f2bf(b.z) | ((unsigned)f2bf(b.w) << 16);
        *(uint4*)(Wgu + row * Dd + dc * 8) = o;
    } else {
        size_t i = ((size_t)(bid - 32768) * blockDim.x + threadIdx.x) * 8;
        float4 a = *(const float4*)(Wd + i);
        float4 b = *(const float4*)(Wd + i + 4);
        uint4 o;
        o.x = (unsigned)f2bf(a.x) | ((unsigned)f2bf(a.y) << 16);
        o.y = (unsigned)f2bf(a.z) | ((unsigned)f2bf(a.w) << 16);
        o.z = (unsigned)f2bf(b.x) | ((unsigned)f2bf(b.y) << 16);
        o.w = (unsigned)f2bf(b.z) | ((unsigned)f2bf(b.w) << 16);
        *(uint4*)(Wdb + i) = o;
    }
}

// ---------------- counts -> offsets + cursors ----------------
__global__ void scan_kernel(const int* __restrict__ counts, int* __restrict__ cursor,
                            int* __restrict__ eoff) {
    if (threadIdx.x == 0) {
        int acc = 0;
        for (int e = 0; e < Ee; ++e) { eoff[e] = acc; cursor[e] = acc; acc += counts[e]; }
        eoff[Ee] = acc;
    }
}

// ---------------- scatter: rows[pos] = 2*t+k ----------------
__global__ void scatter_kernel(const int* __restrict__ ids,
                               int* __restrict__ cursor, int* __restrict__ rows) {
    int t = blockIdx.x * blockDim.x + threadIdx.x;
    if (t >= Tt) return;
#pragma unroll
    for (int k = 0; k < Kk; ++k) {
        int e = ids[2 * t + k];
        int pos = atomicAdd(&cursor[e], 1);
        rows[pos] = 2 * t + k;
    }
}

// =================== 256x256 BK=32 8-wave GEMM body, 2 blocks/CU, 1 barrier/tile ===================
// LDS 64KB: A dbuf 2x16KB @0, B dbuf 2x16KB @32768B. Per tile t: stage(t+1)->buf[(t+1)&1] (4 gl16),
// 12 ds_read_b128 from buf[t&1], 32 MFMA, vmcnt(0), s_barrier. No cross-tile in-flight state:
// race-free by construction (all waves synced per tile; stages target the buffer nobody reads).
// Swizzle: LDS(row, c) holds global chunk c ^ ((row>>1)&3): 4 rotations x bit4-alternation ->
// worst case 2-way bank aliasing on ds_read (free, m136).
// G2=false (g1): A=xb via rows[]>>1, B=Wgu N=8192, K=1024, epi relu(g)*u -> H.
// G2=true  (g2): A=H direct, B=Wdb N=1024, split-K=4 (sK=by&3, koff=sK*1024), epi raw acc -> partial.

#define MFMA_BF16(a, b, c) __builtin_amdgcn_mfma_f32_16x16x32_bf16(a, b, c, 0, 0, 0)

template<bool G2>
__device__ __forceinline__ void gemm_body(unsigned short* Ls,
                                          const unsigned short* __restrict__ Abase,
                                          const unsigned short* __restrict__ Bbase,
                                          const int* __restrict__ eoff,
                                          const int* __restrict__ rows,
                                          unsigned short* __restrict__ H,
                                          float* __restrict__ partial) {
    constexpr int KLEN = G2 ? Ff : Dd;   // physical row length
    constexpr int NT   = 32;             // 1024 K per block / BK=32 (g2: split-K=4)
    const int e   = blockIdx.z;
    const int off = eoff[e];
    const int ne  = eoff[e + 1] - off;
    const int by  = blockIdx.y;
    const int my  = G2 ? (by >> 2) : by;
    const int sK  = G2 ? (by & 3) : 0;
    const int koff = sK * 1024;
    const int m0  = my * 256;
    if (m0 >= ne) return;
    const int n0  = blockIdx.x * 256;

    const int tid  = threadIdx.x;
    const int lane = tid & 63;
    const int w    = tid >> 6;
    const int wr   = w >> 2;
    const int wc   = w & 3;
    const int lr   = lane & 15;
    const int lc   = lane >> 4;

    // staging: lane -> (sr4 row-in-16, c4 chunk-of-16B); pre-swizzled source chunk
    const int sr4 = lane >> 2, c4 = lane & 3;
    const int scA = c4 ^ ((sr4 >> 1) & 3);
    int asrc[2], bsrc[2];
#pragma unroll
    for (int q = 0; q < 2; ++q) {
        int rowq = q * 128 + w * 16 + sr4;
        int rr = m0 + rowq; if (rr > ne - 1) rr = ne - 1;
        asrc[q] = (G2 ? (off + rr) : (rows[off + rr] >> 1)) * KLEN + scA * 8;
        bsrc[q] = (n0 + rowq) * KLEN + scA * 8;
    }
    const unsigned short* Bp = Bbase + (size_t)e * (G2 ? (size_t)Dd * Ff : (size_t)8192 * Dd);

    auto STAGE = [&](int T) {
        const int bo = (T & 1) * 8192; const int kt = koff + T * 32;
        gl16(Abase + asrc[0] + kt, Ls + bo + w * 512);
        gl16(Abase + asrc[1] + kt, Ls + bo + 4096 + w * 512);
        gl16(Bp + bsrc[0] + kt, Ls + 16384 + bo + w * 512);
        gl16(Bp + bsrc[1] + kt, Ls + 16384 + bo + 4096 + w * 512);
    };

    const int ccx = (lc ^ ((lr >> 1) & 3)) * 8;
    const int aB0 = (wr * 128 + lr) * 32 + ccx;   // + bo + m*512
    const int bB0 = (wc * 64 + lr) * 32 + ccx;    // + 16384 + bo + n*512

    f32x4 acc[8][4];
#pragma unroll
    for (int m = 0; m < 8; ++m)
#pragma unroll
        for (int n = 0; n < 4; ++n) acc[m][n] = (f32x4){0.f, 0.f, 0.f, 0.f};

    STAGE(0);
    asm volatile("s_waitcnt vmcnt(0)" ::: "memory");
    __builtin_amdgcn_sched_barrier(0);
    __builtin_amdgcn_s_barrier();

    for (int t = 0; t < NT; ++t) {
        const int bo = (t & 1) * 8192;
        if (t + 1 < NT) STAGE(t + 1);
        bf16x8 a[8], b[4];
#pragma unroll
        for (int m = 0; m < 8; ++m) a[m] = *(const bf16x8*)(Ls + bo + aB0 + m * 512);
#pragma unroll
        for (int n = 0; n < 4; ++n) b[n] = *(const bf16x8*)(Ls + 16384 + bo + bB0 + n * 512);
        __builtin_amdgcn_s_setprio(1);
#pragma unroll
        for (int m = 0; m < 8; ++m)
#pragma unroll
            for (int n = 0; n < 4; ++n)
                acc[m][n] = MFMA_BF16(a[m], b[n], acc[m][n]);
        __builtin_amdgcn_s_setprio(0);
        if (t + 1 < NT) { asm volatile("s_waitcnt vmcnt(0)" ::: "memory"); }
        __builtin_amdgcn_sched_barrier(0);
        __builtin_amdgcn_s_barrier();
    }

    if constexpr (!G2) {
        const int fg16 = ((n0 + wc * 64) >> 5) * 16 + lr;
#pragma unroll
        for (int m = 0; m < 8; ++m) {
            const int itok = m0 + wr * 128 + m * 16 + lc * 4;
#pragma unroll
            for (int r = 0; r < 4; ++r) {
                const int i = itok + r;
                if (i < ne) {
                    unsigned short* hp = H + (size_t)(off + i) * Ff;
#pragma unroll
                    for (int np = 0; np < 2; ++np) {
                        const float g = acc[m][2 * np][r];
                        const float u = acc[m][2 * np + 1][r];
                        hp[fg16 + np * 16] = f2bf(fmaxf(g, 0.f) * u);
                    }
                }
            }
        }
    } else {
        const int dbase = n0 + wc * 64;
#pragma unroll
        for (int m = 0; m < 8; ++m) {
            const int ib = m0 + wr * 128 + m * 16 + lc * 4;
#pragma unroll
            for (int r = 0; r < 4; ++r) {
                const int i = ib + r;
                if (i < ne) {
                    const int tr = rows[off + i];  // 2t+k
                    float* op = partial + ((size_t)sK * 8192 + tr) * Dd + dbase + lr;
#pragma unroll
                    for (int n = 0; n < 4; ++n) op[n * 16] = acc[m][n][r];
                }
            }
        }
    }
}

__global__ __launch_bounds__(512, 4) void g1_moe(const unsigned short* __restrict__ xb,
                                                 const unsigned short* __restrict__ Wgu,
                                                 const int* __restrict__ eoff,
                                                 const int* __restrict__ rows,
                                                 unsigned short* __restrict__ H) {
    __shared__ __align__(16) unsigned short Ls[32768];  // 64 KiB -> 2 blocks/CU
    gemm_body<false>(Ls, xb, Wgu, eoff, rows, H, nullptr);
}

__global__ __launch_bounds__(512, 4) void g2_moe(const unsigned short* __restrict__ H,
                                                 const unsigned short* __restrict__ Wdb,
                                                 const int* __restrict__ eoff,
                                                 const int* __restrict__ rows,
                                                 float* __restrict__ partial) {
    __shared__ __align__(16) unsigned short Ls[32768];
    gemm_body<true>(Ls, H, Wdb, eoff, rows, nullptr, partial);
}

// ---------------- deterministic combine over 4 K-slices ----------------
__global__ void reduce_kernel(const float* __restrict__ P, const float* __restrict__ wts,
                              float* __restrict__ out) {
    const size_t idx = (size_t)blockIdx.x * blockDim.x + threadIdx.x;
    const size_t t  = idx >> 8;
    const int   dq  = (int)(idx & 255);
    const float w0 = wts[2 * t], w1 = wts[2 * t + 1];
    float4 sa = {0.f, 0.f, 0.f, 0.f}, sb = {0.f, 0.f, 0.f, 0.f};
#pragma unroll
    for (int s = 0; s < 4; ++s) {
        float4 a = ((const float4*)(P + ((size_t)s * 8192 + 2 * t) * Dd))[dq];
        float4 b = ((const float4*)(P + ((size_t)s * 8192 + 2 * t + 1) * Dd))[dq];
        sa.x += a.x; sa.y += a.y; sa.z += a.z; sa.w += a.w;
        sb.x += b.x; sb.y += b.y; sb.z += b.z; sb.w += b.w;
    }
    float4 o;
    o.x = w0 * sa.x + w1 * sb.x;
    o.y = w0 * sa.y + w1 * sb.y;
    o.z = w0 * sa.z + w1 * sb.z;
    o.w = w0 * sa.w + w1 * sb.w;
    ((float4*)(out + t * Dd))[dq] = o;
}

extern "C" void kernel_launch(void* const* d_in, const int* in_sizes, int n_in,
                              void* d_out, int out_size, void* d_ws, size_t ws_size,
                              hipStream_t stream) {
    const float* x  = (const float*)d_in[0];
    const float* Wr = (const float*)d_in[1];
    const float* Wg = (const float*)d_in[2];
    const float* Wu = (const float*)d_in[3];
    const float* Wd = (const float*)d_in[4];
    float* out = (float*)d_out;
    char* ws = (char*)d_ws;

    const size_t WELEM    = (size_t)Ee * Ff * Dd;            // 33.55M
    const size_t OFF_IDS  = 256;
    const size_t OFF_WTS  = OFF_IDS  + (size_t)Tt * 2 * 4;
    const size_t OFF_ROWS = OFF_WTS  + (size_t)Tt * 2 * 4;
    const size_t OFF_ROWW = OFF_ROWS + (size_t)Tt * Kk * 4;
    const size_t OFF_XB   = OFF_ROWW + (size_t)Tt * Kk * 4;
    const size_t OFF_H    = OFF_XB   + (size_t)Tt * Dd * 2;
    const size_t OFF_WGU  = OFF_H    + (size_t)Tt * Kk * Ff * 2;
    const size_t OFF_WD   = OFF_WGU  + WELEM * 2 * 2;        // Wgu region 134.2 MB
    const size_t NEED     = OFF_WD   + WELEM * 2;
    if (ws_size < NEED) return;

    int* counts = (int*)ws;
    int* cursor = (int*)(ws + 32);
    int* eoff   = (int*)(ws + 64);
    int* ids    = (int*)(ws + OFF_IDS);
    float* wts  = (float*)(ws + OFF_WTS);
    int* rows   = (int*)(ws + OFF_ROWS);
    unsigned short* xb  = (unsigned short*)(ws + OFF_XB);
    unsigned short* H   = (unsigned short*)(ws + OFF_H);
    unsigned short* Wgu = (unsigned short*)(ws + OFF_WGU);
    unsigned short* Wdb = (unsigned short*)(ws + OFF_WD);
    float* partial = (float*)(ws + OFF_WGU);  // 4 slices x 32 MB = 128 MB < 134.2 MB (dead Wgu)

    hipMemsetAsync(ws, 0, 256, stream);

    router_kernel  <<<Tt, 64, 0, stream>>>(x, Wr, ids, wts, counts, xb);
    scan_kernel    <<<1, 64, 0, stream>>>(counts, cursor, eoff);
    scatter_kernel <<<Tt / 256, 256, 0, stream>>>(ids, cursor, rows);

    cvt_all_kernel <<<49152, 256, 0, stream>>>(Wg, Wu, Wd, Wgu, Wdb);

    g1_moe <<<dim3(2 * Ff / 256, Tt / 256, Ee), 512, 0, stream>>>(xb, Wgu, eoff, rows, H);
    g2_moe <<<dim3(Dd / 256, 4 * (Tt / 256), Ee), 512, 0, stream>>>(H, Wdb, eoff, rows, partial);

    reduce_kernel  <<<(Tt * Dd / 4) / 256, 256, 0, stream>>>(partial, wts, out);
}

// Round 10
// 524.063 us; speedup vs baseline: 5.7019x; 5.7019x over previous
//
#include <hip/hip_runtime.h>
#include <hip/hip_bf16.h>

// Problem constants
#define Tt 4096   // B*L tokens
#define Dd 1024   // model dim
#define Ee 8      // experts
#define Kk 2      // top-k
#define Ff 4096   // DFF

using f32x4  = __attribute__((ext_vector_type(4))) float;
using bf16x8 = __attribute__((ext_vector_type(8))) short;

__device__ __forceinline__ unsigned short f2bf(float f) {
    union { float fp; unsigned int u; } v; v.fp = f;
    unsigned int u = v.u;
    return (unsigned short)((u + 0x7FFFu + ((u >> 16) & 1u)) >> 16);  // RNE
}

__device__ __forceinline__ void gl16(const void* g, void* l) {
    __builtin_amdgcn_global_load_lds(
        (const __attribute__((address_space(1))) void*)g,
        (__attribute__((address_space(3))) void*)l, 16, 0, 0);
}

// ---------------- Router (+ x->bf16): logits fp64, softmax, top-2, renorm ----------------
__global__ void router_kernel(const float* __restrict__ x, const float* __restrict__ Wr,
                              int* __restrict__ ids, float* __restrict__ wts,
                              int* __restrict__ counts, unsigned short* __restrict__ xb) {
    const int t = blockIdx.x;
    const int lane = threadIdx.x;  // 64
    const float* xr = x + (size_t)t * Dd + lane * 16;
    float xv[16];
#pragma unroll
    for (int i = 0; i < 4; ++i) *(float4*)(xv + 4 * i) = *(const float4*)(xr + 4 * i);
    uint4 o0, o1;
    o0.x = (unsigned)f2bf(xv[0])  | ((unsigned)f2bf(xv[1])  << 16);
    o0.y = (unsigned)f2bf(xv[2])  | ((unsigned)f2bf(xv[3])  << 16);
    o0.z = (unsigned)f2bf(xv[4])  | ((unsigned)f2bf(xv[5])  << 16);
    o0.w = (unsigned)f2bf(xv[6])  | ((unsigned)f2bf(xv[7])  << 16);
    o1.x = (unsigned)f2bf(xv[8])  | ((unsigned)f2bf(xv[9])  << 16);
    o1.y = (unsigned)f2bf(xv[10]) | ((unsigned)f2bf(xv[11]) << 16);
    o1.z = (unsigned)f2bf(xv[12]) | ((unsigned)f2bf(xv[13]) << 16);
    o1.w = (unsigned)f2bf(xv[14]) | ((unsigned)f2bf(xv[15]) << 16);
    unsigned short* xo = xb + (size_t)t * Dd + lane * 16;
    *(uint4*)(xo) = o0;
    *(uint4*)(xo + 8) = o1;

    double dot[Ee];
#pragma unroll
    for (int e = 0; e < Ee; ++e) {
        const float* wr = Wr + e * Dd + lane * 16;
        double s = 0.0;
#pragma unroll
        for (int i = 0; i < 16; ++i) s += (double)xv[i] * (double)wr[i];
        dot[e] = s;
    }
#pragma unroll
    for (int off = 32; off >= 1; off >>= 1) {
#pragma unroll
        for (int e = 0; e < Ee; ++e) dot[e] += __shfl_xor(dot[e], off, 64);
    }
    if (lane == 0) {
        float lg[Ee];
#pragma unroll
        for (int e = 0; e < Ee; ++e) lg[e] = (float)dot[e];
        float m = lg[0];
        for (int e = 1; e < Ee; ++e) m = fmaxf(m, lg[e]);
        float ex[Ee]; float sum = 0.f;
        for (int e = 0; e < Ee; ++e) { ex[e] = expf(lg[e] - m); sum += ex[e]; }
        float s0 = -1.f, s1 = -1.f; int i0 = 0, i1 = 0;
        for (int e = 0; e < Ee; ++e) {
            float s = ex[e];
            if (s > s0)      { s1 = s0; i1 = i0; s0 = s; i0 = e; }
            else if (s > s1) { s1 = s; i1 = e; }
        }
        float inv = 1.f / sum;
        float sc0 = s0 * inv, sc1 = s1 * inv;
        float den = sc0 + sc1 + 1.1920929e-7f;
        ids[2 * t] = i0; ids[2 * t + 1] = i1;
        wts[2 * t] = sc0 / den; wts[2 * t + 1] = sc1 / den;
        atomicAdd(&counts[i0], 1);
        atomicAdd(&counts[i1], 1);
    }
}

// ---------------- combined weight convert: Wgu interleave + Wd plain ----------------
__global__ void cvt_all_kernel(const float* __restrict__ Wg, const float* __restrict__ Wu,
                               const float* __restrict__ Wd,
                               unsigned short* __restrict__ Wgu, unsigned short* __restrict__ Wdb) {
    const int bid = blockIdx.x;
    if (bid < 32768) {
        size_t tid = (size_t)bid * blockDim.x + threadIdx.x;
        size_t row = tid >> 7;          // 128 threads per 1024-elem row
        int dc  = (int)(tid & 127);
        int e   = (int)(row >> 13);     // 8192 rows/expert
        int j   = (int)(row & 8191);
        int fg = j >> 5, s = (j >> 4) & 1, fi = j & 15;
        int f  = fg * 16 + fi;
        const float* src = (s ? Wu : Wg) + ((size_t)e * Ff + f) * Dd + dc * 8;
        float4 a = *(const float4*)(src);
        float4 b = *(const float4*)(src + 4);
        uint4 o;
        o.x = (unsigned)f2bf(a.x) | ((unsigned)f2bf(a.y) << 16);
        o.y = (unsigned)f2bf(a.z) | ((unsigned)f2bf(a.w) << 16);
        o.z = (unsigned)f2bf(b.x) | ((unsigned)f2bf(b.y) << 16);
        o.w = (unsigned)f2bf(b.z) | ((unsigned)f2bf(b.w) << 16);
        *(uint4*)(Wgu + row * Dd + dc * 8) = o;
    } else {
        size_t i = ((size_t)(bid - 32768) * blockDim.x + threadIdx.x) * 8;
        float4 a = *(const float4*)(Wd + i);
        float4 b = *(const float4*)(Wd + i + 4);
        uint4 o;
        o.x = (unsigned)f2bf(a.x) | ((unsigned)f2bf(a.y) << 16);
        o.y = (unsigned)f2bf(a.z) | ((unsigned)f2bf(a.w) << 16);
        o.z = (unsigned)f2bf(b.x) | ((unsigned)f2bf(b.y) << 16);
        o.w = (unsigned)f2bf(b.z) | ((unsigned)f2bf(b.w) << 16);
        *(uint4*)(Wdb + i) = o;
    }
}

// ---------------- counts -> offsets + cursors ----------------
__global__ void scan_kernel(const int* __restrict__ counts, int* __restrict__ cursor,
                            int* __restrict__ eoff) {
    if (threadIdx.x == 0) {
        int acc = 0;
        for (int e = 0; e < Ee; ++e) { eoff[e] = acc; cursor[e] = acc; acc += counts[e]; }
        eoff[Ee] = acc;
    }
}

// ---------------- scatter: rows[pos] = 2*t+k ----------------
__global__ void scatter_kernel(const int* __restrict__ ids,
                               int* __restrict__ cursor, int* __restrict__ rows) {
    int t = blockIdx.x * blockDim.x + threadIdx.x;
    if (t >= Tt) return;
#pragma unroll
    for (int k = 0; k < Kk; ++k) {
        int e = ids[2 * t + k];
        int pos = atomicAdd(&cursor[e], 1);
        rows[pos] = 2 * t + k;
    }
}

// =================== r6-proven 256x256 BK=64 8-wave 4-phase counted-vmcnt GEMM ===================
// Inner schedule IDENTICAL to round-6 (517.7 us, verified deterministic).
// NEW (r10): for G2=false the block is persistent over m-tiles: grid (32,1,8)=256 blocks
// (exactly 1/CU), looping my=0..ceil(ne/256)-1. Each m-iteration ends fully drained
// (tail vmcnt(0) + per-phase lgkm drains), so the next prologue cannot race.
// Benefit: no batch-boundary drains, amortized prologue, B-panel (512KB per (n0,e)) L2-resident.

#define MFMA_BF16(a, b, c) __builtin_amdgcn_mfma_f32_16x16x32_bf16(a, b, c, 0, 0, 0)

template<bool G2>
__launch_bounds__(512, 1)
__global__ void gemm_8ph(const unsigned short* __restrict__ Abase,
                         const unsigned short* __restrict__ Bbase,
                         const int* __restrict__ eoff, const int* __restrict__ rows,
                         unsigned short* __restrict__ H,
                         float* __restrict__ partial) {
    constexpr int KLEN = G2 ? Ff : Dd;            // physical A/B row length
    constexpr int NT   = (G2 ? 2048 : 1024) / 64; // K-tiles per m-iteration
    const int e   = blockIdx.z;
    const int off = eoff[e];
    const int ne  = eoff[e + 1] - off;
    const int sK  = G2 ? ((int)blockIdx.y & 1) : 0;
    const int koff = sK * 2048;
    const int n0  = blockIdx.x * 256;

    __shared__ __align__(16) unsigned short Ls[65536];  // 128 KiB

    const int tid  = threadIdx.x;
    const int lane = tid & 63;
    const int w    = tid >> 6;        // wave 0..7
    const int wr   = w >> 2;          // 0..1 (M half)
    const int wc   = w & 3;           // 0..3 (N quarter)
    const int lr   = lane & 15;
    const int lc   = lane >> 4;       // 0..3

    const int sr = lane >> 3;                 // 0..7
    const int cA = (lane & 7) ^ sr;           // pre-swizzled source chunk
    const unsigned short* Bp = Bbase + (size_t)e * (G2 ? (size_t)Dd * Ff : (size_t)8192 * Dd);
    int bsrc[4];
#pragma unroll
    for (int qq = 0; qq < 4; ++qq) {
        int rN = n0 + qq * 64 + w * 8 + sr;
        bsrc[qq] = rN * KLEN + cA * 8;
    }

    const int ccx0 = ((0 * 4 + lc) ^ (lr & 7)) * 8;
    const int ccx1 = ((1 * 4 + lc) ^ (lr & 7)) * 8;
    const int aB = wr * 8192 + lr * 64;
    const int bB = 16384 + wc * 4096 + lr * 64;

    const int myBeg = G2 ? ((int)blockIdx.y >> 1) : 0;
    const int myEnd = G2 ? (myBeg + 1) : ((ne + 255) >> 8);

    for (int my = myBeg; my < myEnd; ++my) {
        const int m0 = my * 256;
        if (m0 >= ne) return;

        int asrc[4];
#pragma unroll
        for (int qq = 0; qq < 4; ++qq) {
            int rr = m0 + qq * 64 + w * 8 + sr;
            if (rr > ne - 1) rr = ne - 1;
            asrc[qq] = (G2 ? (off + rr) : (rows[off + rr] >> 1)) * KLEN + cA * 8;
        }

        auto STAGE_A = [&](int T, int Hh) {
            const int bo_ = (T & 1) * 32768; const int kt_ = koff + T * 64;
            gl16(Abase + asrc[2 * Hh]     + kt_, Ls + bo_ + (2 * Hh)     * 4096 + w * 512);
            gl16(Abase + asrc[2 * Hh + 1] + kt_, Ls + bo_ + (2 * Hh + 1) * 4096 + w * 512);
        };
        auto STAGE_B = [&](int T, int Hh) {
            const int bo_ = (T & 1) * 32768 + 16384; const int kt_ = koff + T * 64;
            gl16(Bp + bsrc[2 * Hh]     + kt_, Ls + bo_ + (2 * Hh)     * 4096 + w * 512);
            gl16(Bp + bsrc[2 * Hh + 1] + kt_, Ls + bo_ + (2 * Hh + 1) * 4096 + w * 512);
        };

        f32x4 acc[8][4];
#pragma unroll
        for (int m = 0; m < 8; ++m)
#pragma unroll
            for (int n = 0; n < 4; ++n) acc[m][n] = (f32x4){0.f, 0.f, 0.f, 0.f};

        // --- prologue: tile0 fully + tile1 A; wait leaves A(1) (4 loads) in flight ---
        STAGE_A(0, 0); STAGE_A(0, 1); STAGE_B(0, 0); STAGE_B(0, 1);
        STAGE_A(1, 0); STAGE_A(1, 1);
        asm volatile("s_waitcnt vmcnt(4)" ::: "memory");
        __builtin_amdgcn_sched_barrier(0);
        __builtin_amdgcn_s_barrier();

        bf16x8 a0[8], a1[8], b0[4], b1[4];

        for (int t = 0; t < NT; ++t) {
            const int bo = (t & 1) * 32768;
            // ---- P1: read a_kk0 + b_kk0; stage (t+1).B0 ----
#pragma unroll
            for (int m = 0; m < 8; ++m) a0[m] = *(const bf16x8*)(Ls + bo + aB + m * 1024 + ccx0);
#pragma unroll
            for (int n = 0; n < 4; ++n) b0[n] = *(const bf16x8*)(Ls + bo + bB + n * 1024 + ccx0);
            if (t + 1 < NT) STAGE_B(t + 1, 0);
            __builtin_amdgcn_s_barrier();
            asm volatile("s_waitcnt lgkmcnt(0)" ::: "memory");
            __builtin_amdgcn_sched_barrier(0);
            __builtin_amdgcn_s_setprio(1);
#pragma unroll
            for (int m = 0; m < 8; ++m) {
                acc[m][0] = MFMA_BF16(a0[m], b0[0], acc[m][0]);
                acc[m][1] = MFMA_BF16(a0[m], b0[1], acc[m][1]);
            }
            __builtin_amdgcn_s_setprio(0);
            __builtin_amdgcn_s_barrier();
            // ---- P2: read a_kk1; stage (t+1).B1; MFMA kk0 nh1; REQUIRED lgkm-drain ----
#pragma unroll
            for (int m = 0; m < 8; ++m) a1[m] = *(const bf16x8*)(Ls + bo + aB + m * 1024 + ccx1);
            if (t + 1 < NT) STAGE_B(t + 1, 1);
            __builtin_amdgcn_s_barrier();
            __builtin_amdgcn_s_setprio(1);
#pragma unroll
            for (int m = 0; m < 8; ++m) {
                acc[m][2] = MFMA_BF16(a0[m], b0[2], acc[m][2]);
                acc[m][3] = MFMA_BF16(a0[m], b0[3], acc[m][3]);
            }
            __builtin_amdgcn_s_setprio(0);
            asm volatile("s_waitcnt lgkmcnt(0)" ::: "memory");
            __builtin_amdgcn_sched_barrier(0);
            __builtin_amdgcn_s_barrier();
            // ---- P3: read b_kk1; stage (t+2).A0; MFMA kk1 nh0 ----
#pragma unroll
            for (int n = 0; n < 4; ++n) b1[n] = *(const bf16x8*)(Ls + bo + bB + n * 1024 + ccx1);
            if (t + 2 < NT) STAGE_A(t + 2, 0);
            __builtin_amdgcn_s_barrier();
            asm volatile("s_waitcnt lgkmcnt(0)" ::: "memory");
            __builtin_amdgcn_sched_barrier(0);
            __builtin_amdgcn_s_setprio(1);
#pragma unroll
            for (int m = 0; m < 8; ++m) {
                acc[m][0] = MFMA_BF16(a1[m], b1[0], acc[m][0]);
                acc[m][1] = MFMA_BF16(a1[m], b1[1], acc[m][1]);
            }
            __builtin_amdgcn_s_setprio(0);
            __builtin_amdgcn_s_barrier();
            // ---- P4: stage (t+2).A1; MFMA kk1 nh1; counted vmcnt (tail-corrected) ----
            if (t + 2 < NT) STAGE_A(t + 2, 1);
            __builtin_amdgcn_s_setprio(1);
#pragma unroll
            for (int m = 0; m < 8; ++m) {
                acc[m][2] = MFMA_BF16(a1[m], b1[2], acc[m][2]);
                acc[m][3] = MFMA_BF16(a1[m], b1[3], acc[m][3]);
            }
            __builtin_amdgcn_s_setprio(0);
            if (t + 2 < NT) { asm volatile("s_waitcnt vmcnt(4)" ::: "memory"); }
            else            { asm volatile("s_waitcnt vmcnt(0)" ::: "memory"); }
            __builtin_amdgcn_sched_barrier(0);
            __builtin_amdgcn_s_barrier();
        }

        if constexpr (!G2) {
            const int fg16 = ((n0 + wc * 64) >> 5) * 16 + lr;
#pragma unroll
            for (int m = 0; m < 8; ++m) {
                const int itok = m0 + wr * 128 + m * 16 + (lane >> 4) * 4;
#pragma unroll
                for (int r = 0; r < 4; ++r) {
                    const int i = itok + r;
                    if (i < ne) {
                        unsigned short* hp = H + (size_t)(off + i) * Ff;
#pragma unroll
                        for (int np = 0; np < 2; ++np) {
                            const float g = acc[m][2 * np][r];
                            const float u = acc[m][2 * np + 1][r];
                            hp[fg16 + np * 16] = f2bf(fmaxf(g, 0.f) * u);
                        }
                    }
                }
            }
        } else {
            const int dbase = n0 + wc * 64;
#pragma unroll
            for (int m = 0; m < 8; ++m) {
                const int ib = m0 + wr * 128 + m * 16 + (lane >> 4) * 4;
#pragma unroll
                for (int r = 0; r < 4; ++r) {
                    const int i = ib + r;
                    if (i < ne) {
                        const int tr = rows[off + i];  // 2t+k, token-determined target
                        float* op = partial + ((size_t)sK * 8192 + tr) * Dd + dbase + lr;
#pragma unroll
                        for (int n = 0; n < 4; ++n) op[n * 16] = acc[m][n][r];
                    }
                }
            }
        }
        __builtin_amdgcn_s_barrier();  // separate m-iterations (epilogue vs next prologue)
    }
}

// ---------------- deterministic combine: out = w0*(P0a+P1a) + w1*(P0b+P1b) ----------------
__global__ void reduce_kernel(const float* __restrict__ P, const float* __restrict__ wts,
                              float* __restrict__ out) {
    const size_t idx = (size_t)blockIdx.x * blockDim.x + threadIdx.x;
    const size_t t  = idx >> 8;
    const int   dq  = (int)(idx & 255);
    const float w0 = wts[2 * t], w1 = wts[2 * t + 1];
    const float4* p00 = (const float4*)(P + (2 * t)        * Dd) + dq;
    const float4* p01 = (const float4*)(P + (2 * t + 1)    * Dd) + dq;
    const float4* p10 = (const float4*)(P + ((size_t)8192 + 2 * t)     * Dd) + dq;
    const float4* p11 = (const float4*)(P + ((size_t)8192 + 2 * t + 1) * Dd) + dq;
    float4 a = *p00, b = *p01, c = *p10, d = *p11;
    float4 o;
    o.x = w0 * (a.x + c.x) + w1 * (b.x + d.x);
    o.y = w0 * (a.y + c.y) + w1 * (b.y + d.y);
    o.z = w0 * (a.z + c.z) + w1 * (b.z + d.z);
    o.w = w0 * (a.w + c.w) + w1 * (b.w + d.w);
    ((float4*)(out + t * Dd))[dq] = o;
}

extern "C" void kernel_launch(void* const* d_in, const int* in_sizes, int n_in,
                              void* d_out, int out_size, void* d_ws, size_t ws_size,
                              hipStream_t stream) {
    const float* x  = (const float*)d_in[0];
    const float* Wr = (const float*)d_in[1];
    const float* Wg = (const float*)d_in[2];
    const float* Wu = (const float*)d_in[3];
    const float* Wd = (const float*)d_in[4];
    float* out = (float*)d_out;
    char* ws = (char*)d_ws;

    const size_t WELEM    = (size_t)Ee * Ff * Dd;            // 33.55M
    const size_t OFF_IDS  = 256;
    const size_t OFF_WTS  = OFF_IDS  + (size_t)Tt * 2 * 4;
    const size_t OFF_ROWS = OFF_WTS  + (size_t)Tt * 2 * 4;
    const size_t OFF_ROWW = OFF_ROWS + (size_t)Tt * Kk * 4;
    const size_t OFF_XB   = OFF_ROWW + (size_t)Tt * Kk * 4;
    const size_t OFF_H    = OFF_XB   + (size_t)Tt * Dd * 2;
    const size_t OFF_WGU  = OFF_H    + (size_t)Tt * Kk * Ff * 2;
    const size_t OFF_WD   = OFF_WGU  + WELEM * 2 * 2;        // Wgu = 2*WELEM bf16
    const size_t NEED     = OFF_WD   + WELEM * 2;            // ~264 MiB
    if (ws_size < NEED) return;

    int* counts = (int*)ws;
    int* cursor = (int*)(ws + 32);
    int* eoff   = (int*)(ws + 64);
    int* ids    = (int*)(ws + OFF_IDS);
    float* wts  = (float*)(ws + OFF_WTS);
    int* rows   = (int*)(ws + OFF_ROWS);
    unsigned short* xb  = (unsigned short*)(ws + OFF_XB);
    unsigned short* H   = (unsigned short*)(ws + OFF_H);
    unsigned short* Wgu = (unsigned short*)(ws + OFF_WGU);
    unsigned short* Wdb = (unsigned short*)(ws + OFF_WD);
    float* partial = (float*)(ws + OFF_WGU);  // 64 MB, aliases Wgu (dead after gemm1)

    hipMemsetAsync(ws, 0, 256, stream);

    router_kernel  <<<Tt, 64, 0, stream>>>(x, Wr, ids, wts, counts, xb);
    scan_kernel    <<<1, 64, 0, stream>>>(counts, cursor, eoff);
    scatter_kernel <<<Tt / 256, 256, 0, stream>>>(ids, cursor, rows);

    cvt_all_kernel <<<49152, 256, 0, stream>>>(Wg, Wu, Wd, Wgu, Wdb);

    gemm_8ph<false><<<dim3(2 * Ff / 256, 1, Ee), 512, 0, stream>>>(
        xb, Wgu, eoff, rows, H, partial);
    gemm_8ph<true> <<<dim3(Dd / 256, 2 * (Tt / 256), Ee), 512, 0, stream>>>(
        H, Wdb, eoff, rows, H, partial);

    reduce_kernel  <<<(Tt * Dd / 4) / 256, 256, 0, stream>>>(partial, wts, out);
}

// Round 11
// 496.274 us; speedup vs baseline: 6.0211x; 1.0560x over previous
//
#include <hip/hip_runtime.h>
#include <hip/hip_bf16.h>

// Problem constants
#define Tt 4096   // B*L tokens
#define Dd 1024   // model dim
#define Ee 8      // experts
#define Kk 2      // top-k
#define Ff 4096   // DFF

using f32x4  = __attribute__((ext_vector_type(4))) float;
using bf16x8 = __attribute__((ext_vector_type(8))) short;

__device__ __forceinline__ unsigned short f2bf(float f) {
    union { float fp; unsigned int u; } v; v.fp = f;
    unsigned int u = v.u;
    return (unsigned short)((u + 0x7FFFu + ((u >> 16) & 1u)) >> 16);  // RNE
}

__device__ __forceinline__ void gl16(const void* g, void* l) {
    __builtin_amdgcn_global_load_lds(
        (const __attribute__((address_space(1))) void*)g,
        (__attribute__((address_space(3))) void*)l, 16, 0, 0);
}

// ---------------- Router (+ x->bf16): logits fp64, softmax, top-2, renorm ----------------
__global__ void router_kernel(const float* __restrict__ x, const float* __restrict__ Wr,
                              int* __restrict__ ids, float* __restrict__ wts,
                              int* __restrict__ counts, unsigned short* __restrict__ xb) {
    const int t = blockIdx.x;
    const int lane = threadIdx.x;  // 64
    const float* xr = x + (size_t)t * Dd + lane * 16;
    float xv[16];
#pragma unroll
    for (int i = 0; i < 4; ++i) *(float4*)(xv + 4 * i) = *(const float4*)(xr + 4 * i);
    uint4 o0, o1;
    o0.x = (unsigned)f2bf(xv[0])  | ((unsigned)f2bf(xv[1])  << 16);
    o0.y = (unsigned)f2bf(xv[2])  | ((unsigned)f2bf(xv[3])  << 16);
    o0.z = (unsigned)f2bf(xv[4])  | ((unsigned)f2bf(xv[5])  << 16);
    o0.w = (unsigned)f2bf(xv[6])  | ((unsigned)f2bf(xv[7])  << 16);
    o1.x = (unsigned)f2bf(xv[8])  | ((unsigned)f2bf(xv[9])  << 16);
    o1.y = (unsigned)f2bf(xv[10]) | ((unsigned)f2bf(xv[11]) << 16);
    o1.z = (unsigned)f2bf(xv[12]) | ((unsigned)f2bf(xv[13]) << 16);
    o1.w = (unsigned)f2bf(xv[14]) | ((unsigned)f2bf(xv[15]) << 16);
    unsigned short* xo = xb + (size_t)t * Dd + lane * 16;
    *(uint4*)(xo) = o0;
    *(uint4*)(xo + 8) = o1;

    double dot[Ee];
#pragma unroll
    for (int e = 0; e < Ee; ++e) {
        const float* wr = Wr + e * Dd + lane * 16;
        double s = 0.0;
#pragma unroll
        for (int i = 0; i < 16; ++i) s += (double)xv[i] * (double)wr[i];
        dot[e] = s;
    }
#pragma unroll
    for (int off = 32; off >= 1; off >>= 1) {
#pragma unroll
        for (int e = 0; e < Ee; ++e) dot[e] += __shfl_xor(dot[e], off, 64);
    }
    if (lane == 0) {
        float lg[Ee];
#pragma unroll
        for (int e = 0; e < Ee; ++e) lg[e] = (float)dot[e];
        float m = lg[0];
        for (int e = 1; e < Ee; ++e) m = fmaxf(m, lg[e]);
        float ex[Ee]; float sum = 0.f;
        for (int e = 0; e < Ee; ++e) { ex[e] = expf(lg[e] - m); sum += ex[e]; }
        float s0 = -1.f, s1 = -1.f; int i0 = 0, i1 = 0;
        for (int e = 0; e < Ee; ++e) {
            float s = ex[e];
            if (s > s0)      { s1 = s0; i1 = i0; s0 = s; i0 = e; }
            else if (s > s1) { s1 = s; i1 = e; }
        }
        float inv = 1.f / sum;
        float sc0 = s0 * inv, sc1 = s1 * inv;
        float den = sc0 + sc1 + 1.1920929e-7f;
        ids[2 * t] = i0; ids[2 * t + 1] = i1;
        wts[2 * t] = sc0 / den; wts[2 * t + 1] = sc1 / den;
        atomicAdd(&counts[i0], 1);
        atomicAdd(&counts[i1], 1);
    }
}

// ---------------- Wg/Wu -> interleaved bf16 Wgu (Wgu only; Wd folded into g1) ----------------
__global__ void cvt_wgu(const float* __restrict__ Wg, const float* __restrict__ Wu,
                        unsigned short* __restrict__ Wgu) {
    size_t tid = (size_t)blockIdx.x * blockDim.x + threadIdx.x;
    size_t row = tid >> 7;          // 128 threads per 1024-elem row
    int dc  = (int)(tid & 127);
    int e   = (int)(row >> 13);     // 8192 rows/expert
    int j   = (int)(row & 8191);
    int fg = j >> 5, s = (j >> 4) & 1, fi = j & 15;
    int f  = fg * 16 + fi;
    const float* src = (s ? Wu : Wg) + ((size_t)e * Ff + f) * Dd + dc * 8;
    float4 a = *(const float4*)(src);
    float4 b = *(const float4*)(src + 4);
    uint4 o;
    o.x = (unsigned)f2bf(a.x) | ((unsigned)f2bf(a.y) << 16);
    o.y = (unsigned)f2bf(a.z) | ((unsigned)f2bf(a.w) << 16);
    o.z = (unsigned)f2bf(b.x) | ((unsigned)f2bf(b.y) << 16);
    o.w = (unsigned)f2bf(b.z) | ((unsigned)f2bf(b.w) << 16);
    *(uint4*)(Wgu + row * Dd + dc * 8) = o;
}

// ---------------- counts -> offsets + cursors ----------------
__global__ void scan_kernel(const int* __restrict__ counts, int* __restrict__ cursor,
                            int* __restrict__ eoff) {
    if (threadIdx.x == 0) {
        int acc = 0;
        for (int e = 0; e < Ee; ++e) { eoff[e] = acc; cursor[e] = acc; acc += counts[e]; }
        eoff[Ee] = acc;
    }
}

// ---------------- scatter: rows[pos] = 2*t+k ----------------
__global__ void scatter_kernel(const int* __restrict__ ids,
                               int* __restrict__ cursor, int* __restrict__ rows) {
    int t = blockIdx.x * blockDim.x + threadIdx.x;
    if (t >= Tt) return;
#pragma unroll
    for (int k = 0; k < Kk; ++k) {
        int e = ids[2 * t + k];
        int pos = atomicAdd(&cursor[e], 1);
        rows[pos] = 2 * t + k;
    }
}

// =================== r6-proven 256x256 BK=64 8-wave 4-phase counted-vmcnt GEMM body ===================
// Schedule byte-identical to round-6 (best measured: 517.7 us total, g1 162 us, deterministic).

#define MFMA_BF16(a, b, c) __builtin_amdgcn_mfma_f32_16x16x32_bf16(a, b, c, 0, 0, 0)

template<bool G2>
__device__ __forceinline__ void gemm_body(unsigned short* Ls,
                                          const unsigned short* __restrict__ Abase,
                                          const unsigned short* __restrict__ Bbase,
                                          const int* __restrict__ eoff,
                                          const int* __restrict__ rows,
                                          unsigned short* __restrict__ H,
                                          float* __restrict__ partial) {
    constexpr int KLEN = G2 ? Ff : Dd;            // physical A/B row length
    constexpr int NT   = (G2 ? 2048 : 1024) / 64; // K-tiles this block processes
    const int e   = blockIdx.z;
    const int off = eoff[e];
    const int ne  = eoff[e + 1] - off;
    const int by  = blockIdx.y;
    const int my  = G2 ? (by >> 1) : by;
    const int sK  = G2 ? (by & 1) : 0;
    const int koff = sK * 2048;
    const int m0  = my * 256;
    if (m0 >= ne) return;
    const int n0  = blockIdx.x * 256;

    const int tid  = threadIdx.x;
    const int lane = tid & 63;
    const int w    = tid >> 6;        // wave 0..7
    const int wr   = w >> 2;          // 0..1 (M half)
    const int wc   = w & 3;           // 0..3 (N quarter)
    const int lr   = lane & 15;
    const int lc   = lane >> 4;       // 0..3

    const int sr = lane >> 3;                 // 0..7
    const int cA = (lane & 7) ^ sr;           // pre-swizzled source chunk
    int asrc[4];
#pragma unroll
    for (int qq = 0; qq < 4; ++qq) {
        int rr = m0 + qq * 64 + w * 8 + sr;
        if (rr > ne - 1) rr = ne - 1;
        asrc[qq] = (G2 ? (off + rr) : (rows[off + rr] >> 1)) * KLEN + cA * 8;
    }
    const unsigned short* Bp = Bbase + (size_t)e * (G2 ? (size_t)Dd * Ff : (size_t)8192 * Dd);
    int bsrc[4];
#pragma unroll
    for (int qq = 0; qq < 4; ++qq) {
        int rN = n0 + qq * 64 + w * 8 + sr;
        bsrc[qq] = rN * KLEN + cA * 8;
    }

    auto STAGE_A = [&](int T, int Hh) {
        const int bo_ = (T & 1) * 32768; const int kt_ = koff + T * 64;
        gl16(Abase + asrc[2 * Hh]     + kt_, Ls + bo_ + (2 * Hh)     * 4096 + w * 512);
        gl16(Abase + asrc[2 * Hh + 1] + kt_, Ls + bo_ + (2 * Hh + 1) * 4096 + w * 512);
    };
    auto STAGE_B = [&](int T, int Hh) {
        const int bo_ = (T & 1) * 32768 + 16384; const int kt_ = koff + T * 64;
        gl16(Bp + bsrc[2 * Hh]     + kt_, Ls + bo_ + (2 * Hh)     * 4096 + w * 512);
        gl16(Bp + bsrc[2 * Hh + 1] + kt_, Ls + bo_ + (2 * Hh + 1) * 4096 + w * 512);
    };

    const int ccx0 = ((0 * 4 + lc) ^ (lr & 7)) * 8;
    const int ccx1 = ((1 * 4 + lc) ^ (lr & 7)) * 8;
    const int aB = wr * 8192 + lr * 64;
    const int bB = 16384 + wc * 4096 + lr * 64;

    f32x4 acc[8][4];
#pragma unroll
    for (int m = 0; m < 8; ++m)
#pragma unroll
        for (int n = 0; n < 4; ++n) acc[m][n] = (f32x4){0.f, 0.f, 0.f, 0.f};

    // --- prologue: tile0 fully + tile1 A; wait leaves A(1) (4 loads) in flight ---
    STAGE_A(0, 0); STAGE_A(0, 1); STAGE_B(0, 0); STAGE_B(0, 1);
    STAGE_A(1, 0); STAGE_A(1, 1);
    asm volatile("s_waitcnt vmcnt(4)" ::: "memory");
    __builtin_amdgcn_sched_barrier(0);
    __builtin_amdgcn_s_barrier();

    bf16x8 a0[8], a1[8], b0[4], b1[4];

    for (int t = 0; t < NT; ++t) {
        const int bo = (t & 1) * 32768;
        // ---- P1: read a_kk0 + b_kk0; stage (t+1).B0 ----
#pragma unroll
        for (int m = 0; m < 8; ++m) a0[m] = *(const bf16x8*)(Ls + bo + aB + m * 1024 + ccx0);
#pragma unroll
        for (int n = 0; n < 4; ++n) b0[n] = *(const bf16x8*)(Ls + bo + bB + n * 1024 + ccx0);
        if (t + 1 < NT) STAGE_B(t + 1, 0);
        __builtin_amdgcn_s_barrier();
        asm volatile("s_waitcnt lgkmcnt(0)" ::: "memory");
        __builtin_amdgcn_sched_barrier(0);
        __builtin_amdgcn_s_setprio(1);
#pragma unroll
        for (int m = 0; m < 8; ++m) {
            acc[m][0] = MFMA_BF16(a0[m], b0[0], acc[m][0]);
            acc[m][1] = MFMA_BF16(a0[m], b0[1], acc[m][1]);
        }
        __builtin_amdgcn_s_setprio(0);
        __builtin_amdgcn_s_barrier();
        // ---- P2: read a_kk1; stage (t+1).B1; MFMA kk0 nh1; REQUIRED lgkm-drain ----
#pragma unroll
        for (int m = 0; m < 8; ++m) a1[m] = *(const bf16x8*)(Ls + bo + aB + m * 1024 + ccx1);
        if (t + 1 < NT) STAGE_B(t + 1, 1);
        __builtin_amdgcn_s_barrier();
        __builtin_amdgcn_s_setprio(1);
#pragma unroll
        for (int m = 0; m < 8; ++m) {
            acc[m][2] = MFMA_BF16(a0[m], b0[2], acc[m][2]);
            acc[m][3] = MFMA_BF16(a0[m], b0[3], acc[m][3]);
        }
        __builtin_amdgcn_s_setprio(0);
        asm volatile("s_waitcnt lgkmcnt(0)" ::: "memory");
        __builtin_amdgcn_sched_barrier(0);
        __builtin_amdgcn_s_barrier();
        // ---- P3: read b_kk1; stage (t+2).A0; MFMA kk1 nh0 ----
#pragma unroll
        for (int n = 0; n < 4; ++n) b1[n] = *(const bf16x8*)(Ls + bo + bB + n * 1024 + ccx1);
        if (t + 2 < NT) STAGE_A(t + 2, 0);
        __builtin_amdgcn_s_barrier();
        asm volatile("s_waitcnt lgkmcnt(0)" ::: "memory");
        __builtin_amdgcn_sched_barrier(0);
        __builtin_amdgcn_s_setprio(1);
#pragma unroll
        for (int m = 0; m < 8; ++m) {
            acc[m][0] = MFMA_BF16(a1[m], b1[0], acc[m][0]);
            acc[m][1] = MFMA_BF16(a1[m], b1[1], acc[m][1]);
        }
        __builtin_amdgcn_s_setprio(0);
        __builtin_amdgcn_s_barrier();
        // ---- P4: stage (t+2).A1; MFMA kk1 nh1; counted vmcnt (tail-corrected) ----
        if (t + 2 < NT) STAGE_A(t + 2, 1);
        __builtin_amdgcn_s_setprio(1);
#pragma unroll
        for (int m = 0; m < 8; ++m) {
            acc[m][2] = MFMA_BF16(a1[m], b1[2], acc[m][2]);
            acc[m][3] = MFMA_BF16(a1[m], b1[3], acc[m][3]);
        }
        __builtin_amdgcn_s_setprio(0);
        if (t + 2 < NT) { asm volatile("s_waitcnt vmcnt(4)" ::: "memory"); }
        else            { asm volatile("s_waitcnt vmcnt(0)" ::: "memory"); }
        __builtin_amdgcn_sched_barrier(0);
        __builtin_amdgcn_s_barrier();
    }

    if constexpr (!G2) {
        const int fg16 = ((n0 + wc * 64) >> 5) * 16 + lr;
#pragma unroll
        for (int m = 0; m < 8; ++m) {
            const int itok = m0 + wr * 128 + m * 16 + (lane >> 4) * 4;
#pragma unroll
            for (int r = 0; r < 4; ++r) {
                const int i = itok + r;
                if (i < ne) {
                    unsigned short* hp = H + (size_t)(off + i) * Ff;
#pragma unroll
                    for (int np = 0; np < 2; ++np) {
                        const float g = acc[m][2 * np][r];
                        const float u = acc[m][2 * np + 1][r];
                        hp[fg16 + np * 16] = f2bf(fmaxf(g, 0.f) * u);
                    }
                }
            }
        }
    } else {
        const int dbase = n0 + wc * 64;
#pragma unroll
        for (int m = 0; m < 8; ++m) {
            const int ib = m0 + wr * 128 + m * 16 + (lane >> 4) * 4;
#pragma unroll
            for (int r = 0; r < 4; ++r) {
                const int i = ib + r;
                if (i < ne) {
                    const int tr = rows[off + i];  // 2t+k, token-determined target
                    float* op = partial + ((size_t)sK * 8192 + tr) * Dd + dbase + lr;
#pragma unroll
                    for (int n = 0; n < 4; ++n) op[n * 16] = acc[m][n][r];
                }
            }
        }
    }
}

// g1: gemm1 + folded Wd fp32->bf16 conversion tail (every block, incl. early-exit ones)
__global__ __launch_bounds__(512, 1)
void g1_moe(const unsigned short* __restrict__ xb, const unsigned short* __restrict__ Wgu,
            const int* __restrict__ eoff, const int* __restrict__ rows,
            unsigned short* __restrict__ H,
            const float* __restrict__ Wd, unsigned short* __restrict__ Wdb) {
    __shared__ __align__(16) unsigned short Ls[65536];  // 128 KiB
    gemm_body<false>(Ls, xb, Wgu, eoff, rows, H, nullptr);
    // Wd convert slice: 4096 blocks x 8192 elems = 33.55M
    const int fb = blockIdx.x + gridDim.x * (blockIdx.y + gridDim.y * blockIdx.z);
    const size_t base = (size_t)fb * 8192;
#pragma unroll
    for (int it = 0; it < 2; ++it) {
        const size_t i = base + (size_t)it * 4096 + threadIdx.x * 8;
        float4 a = *(const float4*)(Wd + i);
        float4 b = *(const float4*)(Wd + i + 4);
        uint4 o;
        o.x = (unsigned)f2bf(a.x) | ((unsigned)f2bf(a.y) << 16);
        o.y = (unsigned)f2bf(a.z) | ((unsigned)f2bf(a.w) << 16);
        o.z = (unsigned)f2bf(b.x) | ((unsigned)f2bf(b.y) << 16);
        o.w = (unsigned)f2bf(b.z) | ((unsigned)f2bf(b.w) << 16);
        *(uint4*)(Wdb + i) = o;
    }
}

__global__ __launch_bounds__(512, 1)
void g2_moe(const unsigned short* __restrict__ H, const unsigned short* __restrict__ Wdb,
            const int* __restrict__ eoff, const int* __restrict__ rows,
            float* __restrict__ partial) {
    __shared__ __align__(16) unsigned short Ls[65536];
    gemm_body<true>(Ls, H, Wdb, eoff, rows, nullptr, partial);
}

// ---------------- deterministic combine: out = w0*(P0a+P1a) + w1*(P0b+P1b) ----------------
__global__ void reduce_kernel(const float* __restrict__ P, const float* __restrict__ wts,
                              float* __restrict__ out) {
    const size_t idx = (size_t)blockIdx.x * blockDim.x + threadIdx.x;
    const size_t t  = idx >> 8;
    const int   dq  = (int)(idx & 255);
    const float w0 = wts[2 * t], w1 = wts[2 * t + 1];
    const float4* p00 = (const float4*)(P + (2 * t)        * Dd) + dq;
    const float4* p01 = (const float4*)(P + (2 * t + 1)    * Dd) + dq;
    const float4* p10 = (const float4*)(P + ((size_t)8192 + 2 * t)     * Dd) + dq;
    const float4* p11 = (const float4*)(P + ((size_t)8192 + 2 * t + 1) * Dd) + dq;
    float4 a = *p00, b = *p01, c = *p10, d = *p11;
    float4 o;
    o.x = w0 * (a.x + c.x) + w1 * (b.x + d.x);
    o.y = w0 * (a.y + c.y) + w1 * (b.y + d.y);
    o.z = w0 * (a.z + c.z) + w1 * (b.z + d.z);
    o.w = w0 * (a.w + c.w) + w1 * (b.w + d.w);
    ((float4*)(out + t * Dd))[dq] = o;
}

extern "C" void kernel_launch(void* const* d_in, const int* in_sizes, int n_in,
                              void* d_out, int out_size, void* d_ws, size_t ws_size,
                              hipStream_t stream) {
    const float* x  = (const float*)d_in[0];
    const float* Wr = (const float*)d_in[1];
    const float* Wg = (const float*)d_in[2];
    const float* Wu = (const float*)d_in[3];
    const float* Wd = (const float*)d_in[4];
    float* out = (float*)d_out;
    char* ws = (char*)d_ws;

    const size_t WELEM    = (size_t)Ee * Ff * Dd;            // 33.55M
    const size_t OFF_IDS  = 256;
    const size_t OFF_WTS  = OFF_IDS  + (size_t)Tt * 2 * 4;
    const size_t OFF_ROWS = OFF_WTS  + (size_t)Tt * 2 * 4;
    const size_t OFF_ROWW = OFF_ROWS + (size_t)Tt * Kk * 4;
    const size_t OFF_XB   = OFF_ROWW + (size_t)Tt * Kk * 4;
    const size_t OFF_H    = OFF_XB   + (size_t)Tt * Dd * 2;
    const size_t OFF_WGU  = OFF_H    + (size_t)Tt * Kk * Ff * 2;
    const size_t OFF_WD   = OFF_WGU  + WELEM * 2 * 2;        // Wgu = 2*WELEM bf16
    const size_t NEED     = OFF_WD   + WELEM * 2;            // ~264 MiB
    if (ws_size < NEED) return;

    int* counts = (int*)ws;
    int* cursor = (int*)(ws + 32);
    int* eoff   = (int*)(ws + 64);
    int* ids    = (int*)(ws + OFF_IDS);
    float* wts  = (float*)(ws + OFF_WTS);
    int* rows   = (int*)(ws + OFF_ROWS);
    unsigned short* xb  = (unsigned short*)(ws + OFF_XB);
    unsigned short* H   = (unsigned short*)(ws + OFF_H);
    unsigned short* Wgu = (unsigned short*)(ws + OFF_WGU);
    unsigned short* Wdb = (unsigned short*)(ws + OFF_WD);
    float* partial = (float*)(ws + OFF_WGU);  // 64 MB, aliases Wgu (dead after g1)

    hipMemsetAsync(ws, 0, 256, stream);

    router_kernel  <<<Tt, 64, 0, stream>>>(x, Wr, ids, wts, counts, xb);
    scan_kernel    <<<1, 64, 0, stream>>>(counts, cursor, eoff);
    scatter_kernel <<<Tt / 256, 256, 0, stream>>>(ids, cursor, rows);

    cvt_wgu        <<<32768, 256, 0, stream>>>(Wg, Wu, Wgu);

    g1_moe <<<dim3(2 * Ff / 256, Tt / 256, Ee), 512, 0, stream>>>(
        xb, Wgu, eoff, rows, H, Wd, Wdb);
    g2_moe <<<dim3(Dd / 256, 2 * (Tt / 256), Ee), 512, 0, stream>>>(
        H, Wdb, eoff, rows, partial);

    reduce_kernel  <<<(Tt * Dd / 4) / 256, 256, 0, stream>>>(partial, wts, out);
}